// Round 9
// baseline (28.616 us; speedup 1.0000x reference)
//
#include <hip/hip_runtime.h>

#define BATCH 1024
#define NANCH 3125
#define LAMB  5.0f

__device__ __forceinline__ float wave_red_f(float v) {
    #pragma unroll
    for (int o = 32; o > 0; o >>= 1) v += __shfl_down(v, o, 64);
    return v;
}

__device__ __forceinline__ float lse2(float cx, float cy) {
    const float m = fmaxf(cx, cy);
    return m + __logf(1.f + __expf(-fabsf(cx - cy)));
}

__device__ __forceinline__ float sl1(float4 p, float4 t) {
    float s4 = 0.f, d, a;
    d = p.x - t.x; a = fabsf(d); s4 += (a < 1.f) ? 0.5f * d * d : a - 0.5f;
    d = p.y - t.y; a = fabsf(d); s4 += (a < 1.f) ? 0.5f * d * d : a - 0.5f;
    d = p.z - t.z; a = fabsf(d); s4 += (a < 1.f) ? 0.5f * d * d : a - 0.5f;
    d = p.w - t.w; a = fabsf(d); s4 += (a < 1.f) ? 0.5f * d * d : a - 0.5f;
    return s4 * 0.25f;
}

// grid = BATCH, block = 1024 (16 waves). One block per batch row; each thread
// owns ONE aligned group of 4 consecutive anchors (781 groups max <= 1024
// threads, no loop). VGPR ~28 -> 2 blocks/CU co-resident = 32 waves/CU (100%
// occupancy ceiling vs R8's 52%). Full per-batch epilogue computed in-block;
// finalize only reads 1024 float2 = 8 KB. No atomics (R3/R7: device-scope
// release atomics trigger the XCD coherence slow path, 2-7x).
__global__ __launch_bounds__(1024) void partial_kernel(
    const float* __restrict__ c_pred,    // [B,N,2]
    const float* __restrict__ r_pred,    // [B,N,4]
    const float* __restrict__ r_target,  // [B,N,4]
    const int*   __restrict__ label,     // [B,N]
    float2*      __restrict__ per_batch) // [B] -> (c_contrib, r_contrib)
{
    const int b   = blockIdx.x;
    const int tid = threadIdx.x;

    const int align0  = (4 - (b & 3)) & 3;       // first 16B-aligned anchor
    const int ngroups = (NANCH - align0) >> 2;   // 780 or 781
    const int ntail   = NANCH - align0 - (ngroups << 2);

    const float*  crow = c_pred + (size_t)b * (NANCH * 2);
    const float4* rp   = (const float4*)(r_pred   + (size_t)b * NANCH * 4);
    const float4* rt   = (const float4*)(r_target + (size_t)b * NANCH * 4);
    const int*    lb   = label + (size_t)b * NANCH;

    float cp = 0.f, cn = 0.f, sl = 0.f, pc = 0.f, nc = 0.f;

    if (tid < ngroups) {
        const int a = align0 + (tid << 2);

        // phase 1: wide label + c loads (3 independent VMEM in flight)
        const int4   L   = *(const int4*)(lb + a);
        const float4 C01 = *(const float4*)(crow + 2 * a);
        const float4 C23 = *(const float4*)(crow + 2 * a + 4);

        // phase 2: issue-only conditional r loads
        const bool p0 = (L.x == 1), p1 = (L.y == 1), p2 = (L.z == 1), p3 = (L.w == 1);
        float4 P0, T0, P1, T1, P2, T2, P3, T3;
        if (p0) { P0 = rp[a];     T0 = rt[a];     }
        if (p1) { P1 = rp[a + 1]; T1 = rt[a + 1]; }
        if (p2) { P2 = rp[a + 2]; T2 = rt[a + 2]; }
        if (p3) { P3 = rp[a + 3]; T3 = rt[a + 3]; }

        // phase 3: consume
        const float e0 = lse2(C01.x, C01.y), e1 = lse2(C01.z, C01.w);
        const float e2 = lse2(C23.x, C23.y), e3 = lse2(C23.z, C23.w);
        const bool n0 = (L.x == 0), n1 = (L.y == 0), n2 = (L.z == 0), n3 = (L.w == 0);

        pc = (p0 ? 1.f : 0.f) + (p1 ? 1.f : 0.f) + (p2 ? 1.f : 0.f) + (p3 ? 1.f : 0.f);
        nc = (n0 ? 1.f : 0.f) + (n1 ? 1.f : 0.f) + (n2 ? 1.f : 0.f) + (n3 ? 1.f : 0.f);
        cp = (p0 ? (e0 - C01.y) : 0.f) + (p1 ? (e1 - C01.w) : 0.f)
           + (p2 ? (e2 - C23.y) : 0.f) + (p3 ? (e3 - C23.w) : 0.f);
        cn = (n0 ? (e0 - C01.x) : 0.f) + (n1 ? (e1 - C01.z) : 0.f)
           + (n2 ? (e2 - C23.x) : 0.f) + (n3 ? (e3 - C23.z) : 0.f);

        if (p0) sl += sl1(P0, T0);
        if (p1) sl += sl1(P1, T1);
        if (p2) sl += sl1(P2, T2);
        if (p3) sl += sl1(P3, T3);
    } else {
        // spare threads: <=5 unaligned head/tail anchors
        const int k = tid - ngroups;
        const int nextra = align0 + ntail;
        if (k < nextra) {
            const int a = (k < align0) ? k
                        : (align0 + (ngroups << 2) + (k - align0));
            const int   l  = lb[a];
            const float cx = crow[2 * a], cy = crow[2 * a + 1];
            const float e  = lse2(cx, cy);
            if (l == 1) {
                pc = 1.f; cp = e - cy;
                sl = sl1(rp[a], rt[a]);
            } else if (l == 0) {
                nc = 1.f; cn = e - cx;
            }
        }
    }

    // wave reduce then cross-wave LDS reduce (16 waves)
    cp = wave_red_f(cp);
    cn = wave_red_f(cn);
    sl = wave_red_f(sl);
    pc = wave_red_f(pc);
    nc = wave_red_f(nc);

    __shared__ float sm[5][16];
    const int wid = tid >> 6, lane = tid & 63;
    if (lane == 0) {
        sm[0][wid] = cp; sm[1][wid] = cn; sm[2][wid] = sl;
        sm[3][wid] = pc; sm[4][wid] = nc;
    }
    __syncthreads();

    if (tid < 64) {
        // 5 stats x 16 waves = 80 values; reduce with one wave
        float v = (tid < 80) ? ((float*)sm)[tid] : 0.f;  // sm[k][w] at k*16+w
        // sum within each 16-slot segment using shuffles
        v += __shfl_down(v, 8, 64);
        v += __shfl_down(v, 4, 64);
        v += __shfl_down(v, 2, 64);
        v += __shfl_down(v, 1, 64);
        // lanes 0,16,32,48 hold sums of stats 0..3; stat 4 is in lanes 64.. -> handled below
        __shared__ float tot[5];
        if ((tid & 15) == 0 && tid < 64) tot[tid >> 4] = v;
        // stat 4 occupies sm flat [64..79]; lanes 0..15 of a second pass:
        if (tid < 16) {
            float w = ((float*)sm)[64 + tid];
            w += __shfl_down(w, 8, 64);
            w += __shfl_down(w, 4, 64);
            w += __shfl_down(w, 2, 64);
            w += __shfl_down(w, 1, 64);
            if (tid == 0) tot[4] = w;
        }
        __builtin_amdgcn_s_barrier();  // wave-local ordering not enough; lanes in same wave though
        if (tid == 0) {
            const float tcp = tot[0], tcn = tot[1], tsl = tot[2];
            const float tpc = tot[3], tnc = tot[4];
            const bool  haspos   = (tpc > 0.5f);
            const float pos_mean = haspos ? tcp / tpc : 0.f;
            const float neg_mean = tcn / fmaxf(tnc, 1.f);
            const float c_contrib = (pos_mean + neg_mean) * 0.5f;
            const float r_contrib = haspos ? tsl / tpc : 0.f;
            per_batch[b] = make_float2(c_contrib, r_contrib);
        }
    }
}

// grid = 1, block = 512. Reduce 1024 float2 (8 KB) -> 3 outputs.
__global__ __launch_bounds__(512) void finalize_kernel(
    const float2* __restrict__ per_batch, // [B]
    float*        __restrict__ out)       // [3]
{
    const int tid = threadIdx.x;
    const float2 v0 = per_batch[tid];
    const float2 v1 = per_batch[tid + 512];
    float c = v0.x + v1.x;
    float r = v0.y + v1.y;

    c = wave_red_f(c);
    r = wave_red_f(r);

    __shared__ float s_c[8], s_r[8];
    const int wid = tid >> 6, lane = tid & 63;
    if (lane == 0) { s_c[wid] = c; s_r[wid] = r; }
    __syncthreads();
    if (tid == 0) {
        float cs = 0.f, rs = 0.f;
        #pragma unroll
        for (int w = 0; w < 8; ++w) { cs += s_c[w]; rs += s_r[w]; }
        const float c_loss = cs / (float)BATCH;
        const float r_loss = rs / (float)BATCH;
        out[0] = c_loss;
        out[1] = r_loss;
        out[2] = c_loss + LAMB * r_loss;
    }
}

extern "C" void kernel_launch(void* const* d_in, const int* in_sizes, int n_in,
                              void* d_out, int out_size, void* d_ws, size_t ws_size,
                              hipStream_t stream) {
    const float* c_pred   = (const float*)d_in[0];
    const float* r_pred   = (const float*)d_in[1];
    const float* r_target = (const float*)d_in[2];
    const int*   label    = (const int*)d_in[3];
    float*       out      = (float*)d_out;
    float2*      per_batch = (float2*)d_ws;   // 1024 * 8 B = 8 KiB

    partial_kernel<<<BATCH, 1024, 0, stream>>>(c_pred, r_pred, r_target, label, per_batch);
    finalize_kernel<<<1, 512, 0, stream>>>(per_batch, out);
}